// Round 2
// baseline (221.067 us; speedup 1.0000x reference)
//
#include <hip/hip_runtime.h>
#include <cstdint>
#include <cstddef>

typedef __attribute__((ext_vector_type(8))) __bf16 bf16x8;
typedef __attribute__((ext_vector_type(4))) float f32x4;

union bf8pack { unsigned short u[8]; bf16x8 v; uint4 q; };

// Fixed bucket capacity: bucket = 32 dst nodes, mean 512 edges, sigma~22.6.
// 768 = mean + 11 sigma -> overflow probability ~1e-29.
#define BCAP 768

static __device__ __forceinline__ unsigned short f2b(float f) {
    union { float f; unsigned int u; } v; v.f = f;
    unsigned int u = v.u;
    unsigned int r = (u + 0x7fffu + ((u >> 16) & 1u)) >> 16;  // RNE
    return (unsigned short)r;
}

// convert 8 consecutive fp32 -> bf16x8 (RNE)
static __device__ __forceinline__ bf16x8 cvt8(const float* __restrict__ p) {
    float4 f0 = *(const float4*)p;
    float4 f1 = *(const float4*)(p + 4);
    bf8pack pk;
    pk.u[0] = f2b(f0.x); pk.u[1] = f2b(f0.y);
    pk.u[2] = f2b(f0.z); pk.u[3] = f2b(f0.w);
    pk.u[4] = f2b(f1.x); pk.u[5] = f2b(f1.y);
    pk.u[6] = f2b(f1.z); pk.u[7] = f2b(f1.w);
    return pk.v;
}

// ---------------------------------------------------------------------------
// mega0 (R1-proven, verbatim): one dispatch, three independent jobs.
//   blocks [0,256)    : edge scatter
//   blocks [256,768)  : k1  y = relu(x @ Wp^T + bp), Wp converted inline
//   blocks [768,1040) : weight convert Wcat/W1_b/W2_b (consumed later)
// ---------------------------------------------------------------------------
__global__ __launch_bounds__(256) void mega0(
    const int* __restrict__ src, const int* __restrict__ dst,
    int* __restrict__ bcnt, unsigned int* __restrict__ pairs,
    const float* __restrict__ x, const float* __restrict__ Wp,
    const float* __restrict__ bp,
    const float* __restrict__ Ws, const float* __restrict__ Wn,
    const float* __restrict__ W1, const float* __restrict__ W2,
    unsigned short* __restrict__ Wcat, unsigned short* __restrict__ W1_b,
    unsigned short* __restrict__ W2_b, unsigned short* __restrict__ y)
{
    const int tid = threadIdx.x;
    const int bx = (int)blockIdx.x;

    if (bx >= 768) {            // ---- weight convert (tail blocks) ----
        int i = (bx - 768) * 256 + tid;
        if (i < 32768) {
            int o = i >> 8, k = i & 255;
            Wcat[i] = f2b(k < 128 ? Ws[o * 128 + k] : Wn[o * 128 + (k - 128)]);
        } else if (i < 65536) {
            W1_b[i - 32768] = f2b(W1[i - 32768]);
        } else {                // i < 69632
            W2_b[i - 65536] = f2b(W2[i - 65536]);
        }
        return;
    }

    if (bx >= 256) {            // ---- k1: y = relu(x @ Wp^T + bp) ----
        const int bm = bx - 256;
        const int w  = tid >> 6;
        const int wm = w & 1, wn = w >> 1;
        const int l  = tid & 63;
        const int lr = l & 15, quad = l >> 4;
        const int m0 = bm * 128 + wm * 64;
        const int n0 = wn * 64;

        f32x4 acc[4][4];
#pragma unroll
        for (int i = 0; i < 4; i++)
#pragma unroll
            for (int j = 0; j < 4; j++) acc[i][j] = (f32x4){0.f, 0.f, 0.f, 0.f};

        const float* Apf = x  + (size_t)(m0 + lr) * 128 + quad * 8;
        const float* Bpf = Wp + (size_t)(n0 + lr) * 128 + quad * 8;

#pragma unroll
        for (int ks = 0; ks < 4; ks++) {
            bf16x8 af[4], bf[4];
#pragma unroll
            for (int i = 0; i < 4; i++)
                af[i] = cvt8(Apf + (size_t)i * 16 * 128 + ks * 32);
#pragma unroll
            for (int i = 0; i < 4; i++)
                bf[i] = cvt8(Bpf + (size_t)i * 16 * 128 + ks * 32);
#pragma unroll
            for (int mi = 0; mi < 4; mi++)
#pragma unroll
                for (int ni = 0; ni < 4; ni++)
                    acc[mi][ni] = __builtin_amdgcn_mfma_f32_16x16x32_bf16(
                        af[mi], bf[ni], acc[mi][ni], 0, 0, 0);
        }

#pragma unroll
        for (int ni = 0; ni < 4; ni++) {
            const int col = n0 + ni * 16 + lr;
            const float bv = bp[col];
#pragma unroll
            for (int mi = 0; mi < 4; mi++) {
#pragma unroll
                for (int r = 0; r < 4; r++) {
                    const int row = m0 + mi * 16 + quad * 4 + r;
                    float v = acc[mi][ni][r] + bv;
                    v = v > 0.f ? v : 0.f;
                    y[(size_t)row * 128 + col] = f2b(v);
                }
            }
        }
        return;
    }

    // ---- scatter (blocks 0..255) ----
    __shared__ int h[2048];
    __shared__ int base_l[2048];
    __shared__ int cnt[2048];
    for (int i = tid; i < 2048; i += 256) { h[i] = 0; cnt[i] = 0; }
    __syncthreads();
    const int base = bx * 4096;
    int d_r[16], s_r[16];
    const int4* s4 = (const int4*)(src + base);
    const int4* d4 = (const int4*)(dst + base);
#pragma unroll
    for (int i = 0; i < 4; i++) {
        int4 dv = d4[tid + i * 256];
        int4 sv = s4[tid + i * 256];
        d_r[i * 4 + 0] = dv.x; d_r[i * 4 + 1] = dv.y;
        d_r[i * 4 + 2] = dv.z; d_r[i * 4 + 3] = dv.w;
        s_r[i * 4 + 0] = sv.x; s_r[i * 4 + 1] = sv.y;
        s_r[i * 4 + 2] = sv.z; s_r[i * 4 + 3] = sv.w;
    }
#pragma unroll
    for (int i = 0; i < 16; i++)
        atomicAdd(&h[((unsigned)d_r[i]) >> 5], 1);
    __syncthreads();
    for (int i = tid; i < 2048; i += 256)
        base_l[i] = h[i] ? (i * BCAP + atomicAdd(&bcnt[i], h[i])) : 0;
    __syncthreads();
#pragma unroll
    for (int i = 0; i < 16; i++) {
        int b = ((unsigned)d_r[i]) >> 5;
        int pos = base_l[b] + atomicAdd(&cnt[b], 1);
        if (pos < (b + 1) * BCAP)   // inert guard (overflow impossible at +11 sigma)
            pairs[pos] = ((unsigned)s_r[i] << 5) | ((unsigned)d_r[i] & 31u);
    }
}

// ---------------------------------------------------------------------------
// bucket_pool3 (R6-proven structure, verbatim): block = bucket of 32 dst
// nodes; counting-sort pairs by dst into LDS, each wave owns 8 nodes,
// 8-deep clamped gather batches, register fmax.
// ---------------------------------------------------------------------------
__global__ __launch_bounds__(256) void bucket_pool3(
    const unsigned int* __restrict__ yu, const int* __restrict__ bcnt,
    const unsigned int* __restrict__ pairs, unsigned short* __restrict__ pooled)
{
    __shared__ unsigned short ldsSrc[1024];
    __shared__ int bin[32], offl[32], cnt2[32];
    const int b = blockIdx.x;
    const int tid = threadIdx.x;
    if (tid < 32) { bin[tid] = 0; cnt2[tid] = 0; }
    __syncthreads();
    const int beg = b * BCAP;
    int nb = bcnt[b]; nb = nb < BCAP ? nb : BCAP;

    for (int i = tid; i < nb; i += 256)
        atomicAdd(&bin[pairs[beg + i] & 31u], 1);
    __syncthreads();
    if (tid == 0) {
        int run = 0;
        for (int i = 0; i < 32; i++) { offl[i] = run; run += bin[i]; }
    }
    __syncthreads();
    for (int i = tid; i < nb; i += 256) {
        unsigned int p = pairs[beg + i];
        int d = p & 31u;
        int slot = offl[d] + atomicAdd(&cnt2[d], 1);
        ldsSrc[slot] = (unsigned short)(p >> 5);
    }
    __syncthreads();

    const int w = tid >> 6, lane = tid & 63;
    for (int ni = 0; ni < 8; ni++) {
        const int n = w * 8 + ni;
        const int e0 = offl[n], cnt = bin[n];
        float ax = 0.f, ay = 0.f;
        for (int e = 0; e < cnt; e += 8) {
            int s[8]; unsigned int v[8];
#pragma unroll
            for (int j = 0; j < 8; j++) {
                int idx = e + j; idx = idx < cnt ? idx : cnt - 1;   // clamp: dup last
                s[j] = ldsSrc[e0 + idx];
            }
#pragma unroll
            for (int j = 0; j < 8; j++) v[j] = yu[(size_t)s[j] * 64 + lane];
#pragma unroll
            for (int j = 0; j < 8; j++) {
                ax = fmaxf(ax, __uint_as_float(v[j] << 16));
                ay = fmaxf(ay, __uint_as_float(v[j] & 0xffff0000u));
            }
        }
        unsigned int packed = (__float_as_uint(ax) >> 16) | (__float_as_uint(ay) & 0xffff0000u);
        ((unsigned int*)pooled)[(size_t)(b * 32 + n) * 64 + lane] = packed;
    }
}

// ---------------------------------------------------------------------------
// k45 v2: 32-row blocks + LDS aliasing for occupancy.
// R1's 64-row version: LDS 51.2KB -> 3 blocks/CU (12 waves, 37.5% cap),
// VGPR 92 -> 5 waves/SIMD; measured Occupancy 20%, dur 52us, latency-bound.
// v2: block = 32 rows, ONE LDS buffer S (16.9KB) time-shared:
//   phase A: h = leaky(concat(bf16(x),pooled) @ Wcat^T + bn) -> S as Hs[32][136]
//   phase B: MFMA loop reads Hs -> sync -> epilogue writes S as H2[32][264]
//   head   : waves 0,1 read H2, out = sigmoid(h2 @ W2^T + b2)
// 16.9KB LDS + VGPR<=~84 (launch_bounds 256,6) -> 6 blocks/CU = 24 waves (75%).
// Grid 2048 blocks (finer tail). Weight panels re-read 2x vs 64-row version —
// L2-resident (~262MB L2 traffic ~7.5us at 35TB/s), not HBM.
// ---------------------------------------------------------------------------
__global__ __launch_bounds__(256, 6) void k45(
    const float* __restrict__ x, const unsigned short* __restrict__ pooled,
    const unsigned short* __restrict__ Wcat, const float* __restrict__ bn,
    const unsigned short* __restrict__ W1_b, const float* __restrict__ b1,
    const unsigned short* __restrict__ W2_b, const float* __restrict__ b2,
    float* __restrict__ out)
{
    __shared__ unsigned short S[32 * 264];   // Hs[32][136] then H2[32][264]
    const int tid = threadIdx.x;
    const int w = tid >> 6, l = tid & 63;
    const int lr = l & 15, quad = l >> 4;
    const int row0 = blockIdx.x * 32;

    // ---- phase A: wave w -> h cols w*32..w*32+31, all 32 rows ----
    {
        f32x4 acc[2][2];
#pragma unroll
        for (int i = 0; i < 2; i++)
#pragma unroll
            for (int j = 0; j < 2; j++) acc[i][j] = (f32x4){0.f, 0.f, 0.f, 0.f};

        const float* Axp = x + (size_t)(row0 + lr) * 128 + quad * 8;
        const unsigned short* App = pooled + (size_t)(row0 + lr) * 128 + quad * 8;
        const unsigned short* Bp = Wcat + (size_t)(w * 32 + lr) * 256 + quad * 8;

#pragma unroll
        for (int ks = 0; ks < 8; ks++) {
            bf16x8 af[2], bf[2];
            if (ks < 4) {       // k 0..127: A = bf16(x)
#pragma unroll
                for (int i = 0; i < 2; i++)
                    af[i] = cvt8(Axp + (size_t)i * 16 * 128 + ks * 32);
            } else {            // k 128..255: A = pooled
#pragma unroll
                for (int i = 0; i < 2; i++)
                    af[i] = *(const bf16x8*)(App + (size_t)i * 16 * 128 + (ks - 4) * 32);
            }
#pragma unroll
            for (int i = 0; i < 2; i++)
                bf[i] = *(const bf16x8*)(Bp + (size_t)i * 16 * 256 + ks * 32);
#pragma unroll
            for (int mi = 0; mi < 2; mi++)
#pragma unroll
                for (int ni = 0; ni < 2; ni++)
                    acc[mi][ni] = __builtin_amdgcn_mfma_f32_16x16x32_bf16(
                        af[mi], bf[ni], acc[mi][ni], 0, 0, 0);
        }

#pragma unroll
        for (int ni = 0; ni < 2; ni++) {
            const int col = w * 32 + ni * 16 + lr;
            const float bv = bn[col];
#pragma unroll
            for (int mi = 0; mi < 2; mi++) {
#pragma unroll
                for (int r = 0; r < 4; r++) {
                    const int row = mi * 16 + quad * 4 + r;   // local
                    float v = acc[mi][ni][r] + bv;
                    v = v > 0.f ? v : 0.01f * v;
                    S[row * 136 + col] = f2b(v);
                }
            }
        }
    }
    __syncthreads();

    // ---- phase B: h2 cols w*64..w*64+63; reads Hs, then rewrites S as H2 ----
    {
        f32x4 acc[2][4];
#pragma unroll
        for (int i = 0; i < 2; i++)
#pragma unroll
            for (int j = 0; j < 4; j++) acc[i][j] = (f32x4){0.f, 0.f, 0.f, 0.f};

        const unsigned short* Bp = W1_b + (size_t)(w * 64 + lr) * 128 + quad * 8;

#pragma unroll
        for (int ks = 0; ks < 4; ks++) {
            bf16x8 af[2], bfr[4];
#pragma unroll
            for (int i = 0; i < 2; i++)
                af[i] = *(const bf16x8*)&S[(i * 16 + lr) * 136 + ks * 32 + quad * 8];
#pragma unroll
            for (int i = 0; i < 4; i++)
                bfr[i] = *(const bf16x8*)(Bp + (size_t)i * 16 * 128 + ks * 32);
#pragma unroll
            for (int mi = 0; mi < 2; mi++)
#pragma unroll
                for (int ni = 0; ni < 4; ni++)
                    acc[mi][ni] = __builtin_amdgcn_mfma_f32_16x16x32_bf16(
                        af[mi], bfr[ni], acc[mi][ni], 0, 0, 0);
        }
        __syncthreads();   // all Hs reads done before S is rewritten as H2

#pragma unroll
        for (int ni = 0; ni < 4; ni++) {
            const int col = w * 64 + ni * 16 + lr;
            const float bv = b1[col];
#pragma unroll
            for (int mi = 0; mi < 2; mi++) {
#pragma unroll
                for (int r = 0; r < 4; r++) {
                    const int row = mi * 16 + quad * 4 + r;   // local
                    float v = acc[mi][ni][r] + bv;
                    v = v > 0.f ? v : 0.01f * v;
                    S[row * 264 + col] = f2b(v);
                }
            }
        }
    }
    __syncthreads();

    // ---- head: waves 0,1 only (16 rows each, full K=256) ----
    if (w < 2) {
        const int m0 = w * 16;
        f32x4 a2 = (f32x4){0.f, 0.f, 0.f, 0.f};
#pragma unroll
        for (int ks = 0; ks < 8; ks++) {
            bf16x8 a = *(const bf16x8*)&S[(m0 + lr) * 264 + ks * 32 + quad * 8];
            bf16x8 bb = *(const bf16x8*)(W2_b + (size_t)lr * 256 + ks * 32 + quad * 8);
            a2 = __builtin_amdgcn_mfma_f32_16x16x32_bf16(a, bb, a2, 0, 0, 0);
        }
        const float bv = b2[lr];
#pragma unroll
        for (int r = 0; r < 4; r++) {
            const int row = row0 + m0 + quad * 4 + r;
            float v = a2[r] + bv;
            out[(size_t)row * 16 + lr] = 1.f / (1.f + __expf(-v));
        }
    }
}

// ---------------------------------------------------------------------------
extern "C" void kernel_launch(void* const* d_in, const int* in_sizes, int n_in,
                              void* d_out, int out_size, void* d_ws, size_t ws_size,
                              hipStream_t stream)
{
    const float* x  = (const float*)d_in[0];
    const float* Wp = (const float*)d_in[1];
    const float* bp = (const float*)d_in[2];
    const float* Ws = (const float*)d_in[3];
    const float* Wn = (const float*)d_in[4];
    const float* bn = (const float*)d_in[5];
    const float* W1 = (const float*)d_in[6];
    const float* b1 = (const float*)d_in[7];
    const float* W2 = (const float*)d_in[8];
    const float* b2 = (const float*)d_in[9];
    const int* src  = (const int*)d_in[10];
    const int* dst  = (const int*)d_in[11];
    float* out = (float*)d_out;

    const int N = in_sizes[0] / 128;   // 65536

    // ws layout:
    //   [ 0,16M)  y      : [N,128] bf16
    //   [16M,32M) pooled : [N,128] bf16
    //   [32M,..)  Wcat (128x256 bf16), W1_b (256x128), W2_b (16x256),
    //             bcnt (2048 ints), pairs (2048*BCAP uints ~6.3MB)
    unsigned short* y      = (unsigned short*)d_ws;
    unsigned short* pooled = (unsigned short*)((char*)d_ws + (size_t)16 * 1024 * 1024);
    unsigned short* Wcat   = (unsigned short*)((char*)d_ws + (size_t)32 * 1024 * 1024);
    unsigned short* W1_b = Wcat + 32768;
    unsigned short* W2_b = W1_b + 32768;
    int* bcnt = (int*)(W2_b + 4096);
    unsigned int* pairs = (unsigned int*)(bcnt + 2048);

    dim3 blk(256);

    hipMemsetAsync(bcnt, 0, 2048 * sizeof(int), stream);

    // scatter (256) | k1 (512) | weight convert (272) — independent jobs,
    // one dispatch; converted weights consumed only by later dispatches.
    mega0<<<1040, blk, 0, stream>>>(src, dst, bcnt, pairs,
                                    x, Wp, bp, Ws, Wn, W1, W2,
                                    Wcat, W1_b, W2_b, y);

    // pool: pooled = segment_max(y[src]) by dst
    bucket_pool3<<<2048, blk, 0, stream>>>((const unsigned int*)y, bcnt, pairs, pooled);

    // fused k4+k5: h, h2 live in LDS only; 32-row blocks, aliased LDS
    k45<<<N / 32, blk, 0, stream>>>(x, pooled, Wcat, bn, W1_b, b1, W2_b, b2, out);
}

// Round 4
// 208.970 us; speedup vs baseline: 1.0579x; 1.0579x over previous
//
#include <hip/hip_runtime.h>
#include <cstdint>
#include <cstddef>

typedef __attribute__((ext_vector_type(8))) __bf16 bf16x8;
typedef __attribute__((ext_vector_type(4))) float f32x4;

union bf8pack { unsigned short u[8]; bf16x8 v; uint4 q; };

// Fixed bucket capacity: bucket = 32 dst nodes, mean 512 edges, sigma~22.6.
// 768 = mean + 11 sigma -> overflow probability ~1e-29.
#define BCAP 768

static __device__ __forceinline__ unsigned short f2b(float f) {
    union { float f; unsigned int u; } v; v.f = f;
    unsigned int u = v.u;
    unsigned int r = (u + 0x7fffu + ((u >> 16) & 1u)) >> 16;  // RNE
    return (unsigned short)r;
}

// convert 8 consecutive fp32 -> bf16x8 (RNE)
static __device__ __forceinline__ bf16x8 cvt8(const float* __restrict__ p) {
    float4 f0 = *(const float4*)p;
    float4 f1 = *(const float4*)(p + 4);
    bf8pack pk;
    pk.u[0] = f2b(f0.x); pk.u[1] = f2b(f0.y);
    pk.u[2] = f2b(f0.z); pk.u[3] = f2b(f0.w);
    pk.u[4] = f2b(f1.x); pk.u[5] = f2b(f1.y);
    pk.u[6] = f2b(f1.z); pk.u[7] = f2b(f1.w);
    return pk.v;
}

// ---------------------------------------------------------------------------
// mega0 (R1-proven, verbatim): one dispatch, three independent jobs.
//   blocks [0,256)    : edge scatter
//   blocks [256,768)  : k1  y = relu(x @ Wp^T + bp), Wp converted inline
//   blocks [768,1040) : weight convert Wcat/W1_b/W2_b (consumed later)
// ---------------------------------------------------------------------------
__global__ __launch_bounds__(256) void mega0(
    const int* __restrict__ src, const int* __restrict__ dst,
    int* __restrict__ bcnt, unsigned int* __restrict__ pairs,
    const float* __restrict__ x, const float* __restrict__ Wp,
    const float* __restrict__ bp,
    const float* __restrict__ Ws, const float* __restrict__ Wn,
    const float* __restrict__ W1, const float* __restrict__ W2,
    unsigned short* __restrict__ Wcat, unsigned short* __restrict__ W1_b,
    unsigned short* __restrict__ W2_b, unsigned short* __restrict__ y)
{
    const int tid = threadIdx.x;
    const int bx = (int)blockIdx.x;

    if (bx >= 768) {            // ---- weight convert (tail blocks) ----
        int i = (bx - 768) * 256 + tid;
        if (i < 32768) {
            int o = i >> 8, k = i & 255;
            Wcat[i] = f2b(k < 128 ? Ws[o * 128 + k] : Wn[o * 128 + (k - 128)]);
        } else if (i < 65536) {
            W1_b[i - 32768] = f2b(W1[i - 32768]);
        } else {                // i < 69632
            W2_b[i - 65536] = f2b(W2[i - 65536]);
        }
        return;
    }

    if (bx >= 256) {            // ---- k1: y = relu(x @ Wp^T + bp) ----
        const int bm = bx - 256;
        const int w  = tid >> 6;
        const int wm = w & 1, wn = w >> 1;
        const int l  = tid & 63;
        const int lr = l & 15, quad = l >> 4;
        const int m0 = bm * 128 + wm * 64;
        const int n0 = wn * 64;

        f32x4 acc[4][4];
#pragma unroll
        for (int i = 0; i < 4; i++)
#pragma unroll
            for (int j = 0; j < 4; j++) acc[i][j] = (f32x4){0.f, 0.f, 0.f, 0.f};

        const float* Apf = x  + (size_t)(m0 + lr) * 128 + quad * 8;
        const float* Bpf = Wp + (size_t)(n0 + lr) * 128 + quad * 8;

#pragma unroll
        for (int ks = 0; ks < 4; ks++) {
            bf16x8 af[4], bf[4];
#pragma unroll
            for (int i = 0; i < 4; i++)
                af[i] = cvt8(Apf + (size_t)i * 16 * 128 + ks * 32);
#pragma unroll
            for (int i = 0; i < 4; i++)
                bf[i] = cvt8(Bpf + (size_t)i * 16 * 128 + ks * 32);
#pragma unroll
            for (int mi = 0; mi < 4; mi++)
#pragma unroll
                for (int ni = 0; ni < 4; ni++)
                    acc[mi][ni] = __builtin_amdgcn_mfma_f32_16x16x32_bf16(
                        af[mi], bf[ni], acc[mi][ni], 0, 0, 0);
        }

#pragma unroll
        for (int ni = 0; ni < 4; ni++) {
            const int col = n0 + ni * 16 + lr;
            const float bv = bp[col];
#pragma unroll
            for (int mi = 0; mi < 4; mi++) {
#pragma unroll
                for (int r = 0; r < 4; r++) {
                    const int row = m0 + mi * 16 + quad * 4 + r;
                    float v = acc[mi][ni][r] + bv;
                    v = v > 0.f ? v : 0.f;
                    y[(size_t)row * 128 + col] = f2b(v);
                }
            }
        }
        return;
    }

    // ---- scatter (blocks 0..255) ----
    __shared__ int h[2048];
    __shared__ int base_l[2048];
    __shared__ int cnt[2048];
    for (int i = tid; i < 2048; i += 256) { h[i] = 0; cnt[i] = 0; }
    __syncthreads();
    const int base = bx * 4096;
    int d_r[16], s_r[16];
    const int4* s4 = (const int4*)(src + base);
    const int4* d4 = (const int4*)(dst + base);
#pragma unroll
    for (int i = 0; i < 4; i++) {
        int4 dv = d4[tid + i * 256];
        int4 sv = s4[tid + i * 256];
        d_r[i * 4 + 0] = dv.x; d_r[i * 4 + 1] = dv.y;
        d_r[i * 4 + 2] = dv.z; d_r[i * 4 + 3] = dv.w;
        s_r[i * 4 + 0] = sv.x; s_r[i * 4 + 1] = sv.y;
        s_r[i * 4 + 2] = sv.z; s_r[i * 4 + 3] = sv.w;
    }
#pragma unroll
    for (int i = 0; i < 16; i++)
        atomicAdd(&h[((unsigned)d_r[i]) >> 5], 1);
    __syncthreads();
    for (int i = tid; i < 2048; i += 256)
        base_l[i] = h[i] ? (i * BCAP + atomicAdd(&bcnt[i], h[i])) : 0;
    __syncthreads();
#pragma unroll
    for (int i = 0; i < 16; i++) {
        int b = ((unsigned)d_r[i]) >> 5;
        int pos = base_l[b] + atomicAdd(&cnt[b], 1);
        if (pos < (b + 1) * BCAP)   // inert guard (overflow impossible at +11 sigma)
            pairs[pos] = ((unsigned)s_r[i] << 5) | ((unsigned)d_r[i] & 31u);
    }
}

// ---------------------------------------------------------------------------
// megaB: pool + k45 fused. Block b owns dst rows [32b, 32b+32) — exactly the
// rows pool-bucket b produces, so pooled NEVER touches global memory.
//   pool  : counting-sort pairs by dst into LDS, gather y, register fmax,
//           epilogue -> PS (LDS, u32-col XOR swizzle: 16-way -> <=2-way on
//           phase-A ds_read_b128)
//   phase A: h = leaky(concat(bf16(x), PS) @ Wcat^T + bn) -> S as Hs[32][136]
//   phase B: h2 = leaky(h @ W1^T + b1): MFMA reads Hs -> sync -> epilogue
//            rewrites S as H2[32][264] (overwrites PS region — dead by then)
//   head  : waves 0,1: out = sigmoid(h2 @ W2^T + b2)
// LDS: S 16.9K + ldsSrc 2K + bins 384B = 19.3K. launch_bounds(256,4): VGPR<=128
// (R2's (256,6) forced VGPR=40 -> spills: WRITE_SIZE doubled + 168us cold
// scratch-alloc dispatch. Never again.) -> 4 blocks/CU, 50% occ, no spill.
// ---------------------------------------------------------------------------
__global__ __launch_bounds__(256, 4) void megaB(
    const unsigned int* __restrict__ yu, const int* __restrict__ bcnt,
    const unsigned int* __restrict__ pairs,
    const float* __restrict__ x,
    const unsigned short* __restrict__ Wcat, const float* __restrict__ bn,
    const unsigned short* __restrict__ W1_b, const float* __restrict__ b1,
    const unsigned short* __restrict__ W2_b, const float* __restrict__ b2,
    float* __restrict__ out)
{
    __shared__ unsigned short S[32 * 264];   // Hs[32][136]+PS | then H2[32][264]
    __shared__ unsigned short ldsSrc[1024];
    __shared__ int bin[32], offl[32], cnt2[32];
    unsigned int* PS = (unsigned int*)&S[32 * 136];   // pooled[32][64] u32, swizzled

    const int b = blockIdx.x;
    const int tid = threadIdx.x;
    const int w = tid >> 6, l = tid & 63;
    const int lr = l & 15, quad = l >> 4;
    const int row0 = b * 32;

    // ---- pool phase (R6-proven gather; epilogue -> LDS with XOR swizzle) ----
    if (tid < 32) { bin[tid] = 0; cnt2[tid] = 0; }
    __syncthreads();
    const int beg = b * BCAP;
    int nb = bcnt[b]; nb = nb < BCAP ? nb : BCAP;

    for (int i = tid; i < nb; i += 256)
        atomicAdd(&bin[pairs[beg + i] & 31u], 1);
    __syncthreads();
    if (tid == 0) {
        int run = 0;
        for (int i = 0; i < 32; i++) { offl[i] = run; run += bin[i]; }
    }
    __syncthreads();
    for (int i = tid; i < nb; i += 256) {
        unsigned int p = pairs[beg + i];
        int d = p & 31u;
        int slot = offl[d] + atomicAdd(&cnt2[d], 1);
        ldsSrc[slot] = (unsigned short)(p >> 5);
    }
    __syncthreads();

    for (int ni = 0; ni < 8; ni++) {
        const int n = w * 8 + ni;
        const int e0 = offl[n], cnt = bin[n];
        float ax = 0.f, ay = 0.f;
        for (int e = 0; e < cnt; e += 8) {
            int s[8]; unsigned int v[8];
#pragma unroll
            for (int j = 0; j < 8; j++) {
                int idx = e + j; idx = idx < cnt ? idx : cnt - 1;   // clamp: dup last
                s[j] = ldsSrc[e0 + idx];
            }
#pragma unroll
            for (int j = 0; j < 8; j++) v[j] = yu[(size_t)s[j] * 64 + l];
#pragma unroll
            for (int j = 0; j < 8; j++) {
                ax = fmaxf(ax, __uint_as_float(v[j] << 16));
                ay = fmaxf(ay, __uint_as_float(v[j] & 0xffff0000u));
            }
        }
        unsigned int packed = (__float_as_uint(ax) >> 16) | (__float_as_uint(ay) & 0xffff0000u);
        // swizzled write: lane l -> u32 col l ^ ((n&7)<<2); bijective per row,
        // conflict-free (permutation within 32-lane groups)
        PS[n * 64 + (l ^ ((n & 7) << 2))] = packed;
    }
    __syncthreads();

    // ---- phase A: wave w -> h cols w*32..w*32+31, all 32 rows ----
    {
        f32x4 acc[2][2];
#pragma unroll
        for (int i = 0; i < 2; i++)
#pragma unroll
            for (int j = 0; j < 2; j++) acc[i][j] = (f32x4){0.f, 0.f, 0.f, 0.f};

        const float* Axp = x + (size_t)(row0 + lr) * 128 + quad * 8;
        const unsigned short* Bp = Wcat + (size_t)(w * 32 + lr) * 256 + quad * 8;

#pragma unroll
        for (int ks = 0; ks < 8; ks++) {
            bf16x8 af[2], bf[2];
            if (ks < 4) {       // k 0..127: A = bf16(x) from global (L3-warm)
#pragma unroll
                for (int i = 0; i < 2; i++)
                    af[i] = cvt8(Axp + (size_t)i * 16 * 128 + ks * 32);
            } else {            // k 128..255: A = pooled from LDS (swizzled)
#pragma unroll
                for (int i = 0; i < 2; i++) {
                    const int row = i * 16 + lr;
                    const int c0 = (ks - 4) * 16 + quad * 4;   // u32 col, mult of 4
                    af[i] = *(const bf16x8*)&PS[row * 64 + (c0 ^ ((row & 7) << 2))];
                }
            }
#pragma unroll
            for (int i = 0; i < 2; i++)
                bf[i] = *(const bf16x8*)(Bp + (size_t)i * 16 * 256 + ks * 32);
#pragma unroll
            for (int mi = 0; mi < 2; mi++)
#pragma unroll
                for (int ni = 0; ni < 2; ni++)
                    acc[mi][ni] = __builtin_amdgcn_mfma_f32_16x16x32_bf16(
                        af[mi], bf[ni], acc[mi][ni], 0, 0, 0);
        }

#pragma unroll
        for (int ni = 0; ni < 2; ni++) {
            const int col = w * 32 + ni * 16 + lr;
            const float bv = bn[col];
#pragma unroll
            for (int mi = 0; mi < 2; mi++) {
#pragma unroll
                for (int r = 0; r < 4; r++) {
                    const int row = mi * 16 + quad * 4 + r;   // local
                    float v = acc[mi][ni][r] + bv;
                    v = v > 0.f ? v : 0.01f * v;
                    S[row * 136 + col] = f2b(v);
                }
            }
        }
    }
    __syncthreads();

    // ---- phase B: h2 cols w*64..w*64+63; reads Hs, then rewrites S as H2 ----
    {
        f32x4 acc[2][4];
#pragma unroll
        for (int i = 0; i < 2; i++)
#pragma unroll
            for (int j = 0; j < 4; j++) acc[i][j] = (f32x4){0.f, 0.f, 0.f, 0.f};

        const unsigned short* Bp = W1_b + (size_t)(w * 64 + lr) * 128 + quad * 8;

#pragma unroll
        for (int ks = 0; ks < 4; ks++) {
            bf16x8 af[2], bfr[4];
#pragma unroll
            for (int i = 0; i < 2; i++)
                af[i] = *(const bf16x8*)&S[(i * 16 + lr) * 136 + ks * 32 + quad * 8];
#pragma unroll
            for (int i = 0; i < 4; i++)
                bfr[i] = *(const bf16x8*)(Bp + (size_t)i * 16 * 128 + ks * 32);
#pragma unroll
            for (int mi = 0; mi < 2; mi++)
#pragma unroll
                for (int ni = 0; ni < 4; ni++)
                    acc[mi][ni] = __builtin_amdgcn_mfma_f32_16x16x32_bf16(
                        af[mi], bfr[ni], acc[mi][ni], 0, 0, 0);
        }
        __syncthreads();   // all Hs reads done before S is rewritten as H2

#pragma unroll
        for (int ni = 0; ni < 4; ni++) {
            const int col = w * 64 + ni * 16 + lr;
            const float bv = b1[col];
#pragma unroll
            for (int mi = 0; mi < 2; mi++) {
#pragma unroll
                for (int r = 0; r < 4; r++) {
                    const int row = mi * 16 + quad * 4 + r;   // local
                    float v = acc[mi][ni][r] + bv;
                    v = v > 0.f ? v : 0.01f * v;
                    S[row * 264 + col] = f2b(v);
                }
            }
        }
    }
    __syncthreads();

    // ---- head: waves 0,1 only (16 rows each, full K=256) ----
    if (w < 2) {
        const int m0 = w * 16;
        f32x4 a2 = (f32x4){0.f, 0.f, 0.f, 0.f};
#pragma unroll
        for (int ks = 0; ks < 8; ks++) {
            bf16x8 a = *(const bf16x8*)&S[(m0 + lr) * 264 + ks * 32 + quad * 8];
            bf16x8 bb = *(const bf16x8*)(W2_b + (size_t)lr * 256 + ks * 32 + quad * 8);
            a2 = __builtin_amdgcn_mfma_f32_16x16x32_bf16(a, bb, a2, 0, 0, 0);
        }
        const float bv = b2[lr];
#pragma unroll
        for (int r = 0; r < 4; r++) {
            const int row = row0 + m0 + quad * 4 + r;
            float v = a2[r] + bv;
            out[(size_t)row * 16 + lr] = 1.f / (1.f + __expf(-v));
        }
    }
}

// ---------------------------------------------------------------------------
extern "C" void kernel_launch(void* const* d_in, const int* in_sizes, int n_in,
                              void* d_out, int out_size, void* d_ws, size_t ws_size,
                              hipStream_t stream)
{
    const float* x  = (const float*)d_in[0];
    const float* Wp = (const float*)d_in[1];
    const float* bp = (const float*)d_in[2];
    const float* Ws = (const float*)d_in[3];
    const float* Wn = (const float*)d_in[4];
    const float* bn = (const float*)d_in[5];
    const float* W1 = (const float*)d_in[6];
    const float* b1 = (const float*)d_in[7];
    const float* W2 = (const float*)d_in[8];
    const float* b2 = (const float*)d_in[9];
    const int* src  = (const int*)d_in[10];
    const int* dst  = (const int*)d_in[11];
    float* out = (float*)d_out;

    const int N = in_sizes[0] / 128;   // 65536

    // ws layout:
    //   [ 0,16M)  y : [N,128] bf16
    //   [16M,..)  Wcat (128x256 bf16), W1_b (256x128), W2_b (16x256),
    //             bcnt (2048 ints), pairs (2048*BCAP uints ~6.3MB)
    unsigned short* y    = (unsigned short*)d_ws;
    unsigned short* Wcat = (unsigned short*)((char*)d_ws + (size_t)16 * 1024 * 1024);
    unsigned short* W1_b = Wcat + 32768;
    unsigned short* W2_b = W1_b + 32768;
    int* bcnt = (int*)(W2_b + 4096);
    unsigned int* pairs = (unsigned int*)(bcnt + 2048);

    dim3 blk(256);

    hipMemsetAsync(bcnt, 0, 2048 * sizeof(int), stream);

    // scatter (256) | k1 (512) | weight convert (272) — independent jobs,
    // one dispatch; converted weights consumed only by later dispatches.
    mega0<<<1040, blk, 0, stream>>>(src, dst, bcnt, pairs,
                                    x, Wp, bp, Ws, Wn, W1, W2,
                                    Wcat, W1_b, W2_b, y);

    // pool + k4 + k5 fused: pooled, h, h2 all live in LDS only
    megaB<<<N / 32, blk, 0, stream>>>((const unsigned int*)y, bcnt, pairs,
                                      x, Wcat, bn, W1_b, b1, W2_b, b2, out);
}

// Round 5
// 206.244 us; speedup vs baseline: 1.0719x; 1.0132x over previous
//
#include <hip/hip_runtime.h>
#include <cstdint>
#include <cstddef>

typedef __attribute__((ext_vector_type(8))) __bf16 bf16x8;
typedef __attribute__((ext_vector_type(4))) float f32x4;

union bf8pack { unsigned short u[8]; bf16x8 v; uint4 q; };

// Fixed bucket capacity: bucket = 32 dst nodes, mean 512 edges, sigma~22.6.
// 768 = mean + 11 sigma -> overflow probability ~1e-29.
#define BCAP 768

static __device__ __forceinline__ unsigned short f2b(float f) {
    union { float f; unsigned int u; } v; v.f = f;
    unsigned int u = v.u;
    unsigned int r = (u + 0x7fffu + ((u >> 16) & 1u)) >> 16;  // RNE
    return (unsigned short)r;
}

// convert 8 consecutive fp32 -> bf16x8 (RNE)
static __device__ __forceinline__ bf16x8 cvt8(const float* __restrict__ p) {
    float4 f0 = *(const float4*)p;
    float4 f1 = *(const float4*)(p + 4);
    bf8pack pk;
    pk.u[0] = f2b(f0.x); pk.u[1] = f2b(f0.y);
    pk.u[2] = f2b(f0.z); pk.u[3] = f2b(f0.w);
    pk.u[4] = f2b(f1.x); pk.u[5] = f2b(f1.y);
    pk.u[6] = f2b(f1.z); pk.u[7] = f2b(f1.w);
    return pk.v;
}

// ---------------------------------------------------------------------------
// mega0: one dispatch, three independent jobs.
//   blocks [0,256)    : edge scatter
//   blocks [256,768)  : k1  y = relu(x @ Wp^T + bp), Wp converted inline;
//                       wn==0 waves ALSO write xb = bf16(x) (R0-proven store,
//                       stride 128) — megaB re-reads xb 4x/block; bf16 1x
//                       materialize beats 4x fp32 re-read + 4x cvt VALU
//                       (R4: megaB FETCH 123MB vs ~55MB ideal, VALU 28%).
//   blocks [768,1040) : weight convert Wcat/W1_b/W2_b (consumed later)
// ---------------------------------------------------------------------------
__global__ __launch_bounds__(256) void mega0(
    const int* __restrict__ src, const int* __restrict__ dst,
    int* __restrict__ bcnt, unsigned int* __restrict__ pairs,
    const float* __restrict__ x, const float* __restrict__ Wp,
    const float* __restrict__ bp,
    const float* __restrict__ Ws, const float* __restrict__ Wn,
    const float* __restrict__ W1, const float* __restrict__ W2,
    unsigned short* __restrict__ Wcat, unsigned short* __restrict__ W1_b,
    unsigned short* __restrict__ W2_b, unsigned short* __restrict__ y,
    unsigned short* __restrict__ xb)
{
    const int tid = threadIdx.x;
    const int bx = (int)blockIdx.x;

    if (bx >= 768) {            // ---- weight convert (tail blocks) ----
        int i = (bx - 768) * 256 + tid;
        if (i < 32768) {
            int o = i >> 8, k = i & 255;
            Wcat[i] = f2b(k < 128 ? Ws[o * 128 + k] : Wn[o * 128 + (k - 128)]);
        } else if (i < 65536) {
            W1_b[i - 32768] = f2b(W1[i - 32768]);
        } else {                // i < 69632
            W2_b[i - 65536] = f2b(W2[i - 65536]);
        }
        return;
    }

    if (bx >= 256) {            // ---- k1: y = relu(x @ Wp^T + bp) + xb ----
        const int bm = bx - 256;
        const int w  = tid >> 6;
        const int wm = w & 1, wn = w >> 1;
        const int l  = tid & 63;
        const int lr = l & 15, quad = l >> 4;
        const int m0 = bm * 128 + wm * 64;
        const int n0 = wn * 64;

        f32x4 acc[4][4];
#pragma unroll
        for (int i = 0; i < 4; i++)
#pragma unroll
            for (int j = 0; j < 4; j++) acc[i][j] = (f32x4){0.f, 0.f, 0.f, 0.f};

        const float* Apf = x  + (size_t)(m0 + lr) * 128 + quad * 8;
        const float* Bpf = Wp + (size_t)(n0 + lr) * 128 + quad * 8;

#pragma unroll
        for (int ks = 0; ks < 4; ks++) {
            bf16x8 af[4], bf[4];
#pragma unroll
            for (int i = 0; i < 4; i++) {
                const float* p = Apf + (size_t)i * 16 * 128 + ks * 32;
                float4 f0 = *(const float4*)p;
                float4 f1 = *(const float4*)(p + 4);
                bf8pack pk;
                pk.u[0] = f2b(f0.x); pk.u[1] = f2b(f0.y);
                pk.u[2] = f2b(f0.z); pk.u[3] = f2b(f0.w);
                pk.u[4] = f2b(f1.x); pk.u[5] = f2b(f1.y);
                pk.u[6] = f2b(f1.z); pk.u[7] = f2b(f1.w);
                af[i] = pk.v;
                if (wn == 0)   // materialize xb once (waves w=0,1 cover all rows)
                    *(uint4*)(xb + (size_t)(m0 + lr + i * 16) * 128 + ks * 32 + quad * 8) = pk.q;
            }
#pragma unroll
            for (int i = 0; i < 4; i++)
                bf[i] = cvt8(Bpf + (size_t)i * 16 * 128 + ks * 32);
#pragma unroll
            for (int mi = 0; mi < 4; mi++)
#pragma unroll
                for (int ni = 0; ni < 4; ni++)
                    acc[mi][ni] = __builtin_amdgcn_mfma_f32_16x16x32_bf16(
                        af[mi], bf[ni], acc[mi][ni], 0, 0, 0);
        }

#pragma unroll
        for (int ni = 0; ni < 4; ni++) {
            const int col = n0 + ni * 16 + lr;
            const float bv = bp[col];
#pragma unroll
            for (int mi = 0; mi < 4; mi++) {
#pragma unroll
                for (int r = 0; r < 4; r++) {
                    const int row = m0 + mi * 16 + quad * 4 + r;
                    float v = acc[mi][ni][r] + bv;
                    v = v > 0.f ? v : 0.f;
                    y[(size_t)row * 128 + col] = f2b(v);
                }
            }
        }
        return;
    }

    // ---- scatter (blocks 0..255) ----
    __shared__ int h[2048];
    __shared__ int base_l[2048];
    __shared__ int cnt[2048];
    for (int i = tid; i < 2048; i += 256) { h[i] = 0; cnt[i] = 0; }
    __syncthreads();
    const int base = bx * 4096;
    int d_r[16], s_r[16];
    const int4* s4 = (const int4*)(src + base);
    const int4* d4 = (const int4*)(dst + base);
#pragma unroll
    for (int i = 0; i < 4; i++) {
        int4 dv = d4[tid + i * 256];
        int4 sv = s4[tid + i * 256];
        d_r[i * 4 + 0] = dv.x; d_r[i * 4 + 1] = dv.y;
        d_r[i * 4 + 2] = dv.z; d_r[i * 4 + 3] = dv.w;
        s_r[i * 4 + 0] = sv.x; s_r[i * 4 + 1] = sv.y;
        s_r[i * 4 + 2] = sv.z; s_r[i * 4 + 3] = sv.w;
    }
#pragma unroll
    for (int i = 0; i < 16; i++)
        atomicAdd(&h[((unsigned)d_r[i]) >> 5], 1);
    __syncthreads();
    for (int i = tid; i < 2048; i += 256)
        base_l[i] = h[i] ? (i * BCAP + atomicAdd(&bcnt[i], h[i])) : 0;
    __syncthreads();
#pragma unroll
    for (int i = 0; i < 16; i++) {
        int b = ((unsigned)d_r[i]) >> 5;
        int pos = base_l[b] + atomicAdd(&cnt[b], 1);
        if (pos < (b + 1) * BCAP)   // inert guard (overflow impossible at +11 sigma)
            pairs[pos] = ((unsigned)s_r[i] << 5) | ((unsigned)d_r[i] & 31u);
    }
}

// ---------------------------------------------------------------------------
// megaB: pool + k45 fused. Block b owns dst rows [32b, 32b+32).
//   pool  : counting-sort pairs by dst into LDS, gather y, register fmax,
//           epilogue -> PS (LDS, u32-col XOR swizzle)
//   phase A: h = leaky(concat(xb, PS) @ Wcat^T + bn) -> S as Hs[32][136].
//           A-side from global xb (bf16, b128 loads, NO cvt) — R4's inline
//           fp32 cvt read the same panel 4x/block = 128MB + 25us VALU.
//   phase B: h2 = leaky(h @ W1^T + b1): reads Hs -> sync -> S as H2[32][264]
//   head  : waves 0,1: out = sigmoid(h2 @ W2^T + b2)
// LDS 19.3K; launch_bounds(256,4): VGPR<=128, no spill (R2 lesson).
// ---------------------------------------------------------------------------
__global__ __launch_bounds__(256, 4) void megaB(
    const unsigned int* __restrict__ yu, const int* __restrict__ bcnt,
    const unsigned int* __restrict__ pairs,
    const unsigned short* __restrict__ xb,
    const unsigned short* __restrict__ Wcat, const float* __restrict__ bn,
    const unsigned short* __restrict__ W1_b, const float* __restrict__ b1,
    const unsigned short* __restrict__ W2_b, const float* __restrict__ b2,
    float* __restrict__ out)
{
    __shared__ unsigned short S[32 * 264];   // Hs[32][136]+PS | then H2[32][264]
    __shared__ unsigned short ldsSrc[1024];
    __shared__ int bin[32], offl[32], cnt2[32];
    unsigned int* PS = (unsigned int*)&S[32 * 136];   // pooled[32][64] u32, swizzled

    const int b = blockIdx.x;
    const int tid = threadIdx.x;
    const int w = tid >> 6, l = tid & 63;
    const int lr = l & 15, quad = l >> 4;
    const int row0 = b * 32;

    // ---- pool phase (R6-proven gather; epilogue -> LDS with XOR swizzle) ----
    if (tid < 32) { bin[tid] = 0; cnt2[tid] = 0; }
    __syncthreads();
    const int beg = b * BCAP;
    int nb = bcnt[b]; nb = nb < BCAP ? nb : BCAP;

    for (int i = tid; i < nb; i += 256)
        atomicAdd(&bin[pairs[beg + i] & 31u], 1);
    __syncthreads();
    if (tid == 0) {
        int run = 0;
        for (int i = 0; i < 32; i++) { offl[i] = run; run += bin[i]; }
    }
    __syncthreads();
    for (int i = tid; i < nb; i += 256) {
        unsigned int p = pairs[beg + i];
        int d = p & 31u;
        int slot = offl[d] + atomicAdd(&cnt2[d], 1);
        ldsSrc[slot] = (unsigned short)(p >> 5);
    }
    __syncthreads();

    for (int ni = 0; ni < 8; ni++) {
        const int n = w * 8 + ni;
        const int e0 = offl[n], cnt = bin[n];
        float ax = 0.f, ay = 0.f;
        for (int e = 0; e < cnt; e += 8) {
            int s[8]; unsigned int v[8];
#pragma unroll
            for (int j = 0; j < 8; j++) {
                int idx = e + j; idx = idx < cnt ? idx : cnt - 1;   // clamp: dup last
                s[j] = ldsSrc[e0 + idx];
            }
#pragma unroll
            for (int j = 0; j < 8; j++) v[j] = yu[(size_t)s[j] * 64 + l];
#pragma unroll
            for (int j = 0; j < 8; j++) {
                ax = fmaxf(ax, __uint_as_float(v[j] << 16));
                ay = fmaxf(ay, __uint_as_float(v[j] & 0xffff0000u));
            }
        }
        unsigned int packed = (__float_as_uint(ax) >> 16) | (__float_as_uint(ay) & 0xffff0000u);
        // swizzled write: lane l -> u32 col l ^ ((n&7)<<2); bijective per row,
        // conflict-free (permutation within 32-lane groups)
        PS[n * 64 + (l ^ ((n & 7) << 2))] = packed;
    }
    __syncthreads();

    // ---- phase A: wave w -> h cols w*32..w*32+31, all 32 rows ----
    {
        f32x4 acc[2][2];
#pragma unroll
        for (int i = 0; i < 2; i++)
#pragma unroll
            for (int j = 0; j < 2; j++) acc[i][j] = (f32x4){0.f, 0.f, 0.f, 0.f};

        const unsigned short* Axp = xb + (size_t)(row0 + lr) * 128 + quad * 8;
        const unsigned short* Bp = Wcat + (size_t)(w * 32 + lr) * 256 + quad * 8;

#pragma unroll
        for (int ks = 0; ks < 8; ks++) {
            bf16x8 af[2], bf[2];
            if (ks < 4) {       // k 0..127: A = xb (bf16, L2/L3-warm, no cvt)
#pragma unroll
                for (int i = 0; i < 2; i++)
                    af[i] = *(const bf16x8*)(Axp + (size_t)i * 16 * 128 + ks * 32);
            } else {            // k 128..255: A = pooled from LDS (swizzled)
#pragma unroll
                for (int i = 0; i < 2; i++) {
                    const int row = i * 16 + lr;
                    const int c0 = (ks - 4) * 16 + quad * 4;   // u32 col, mult of 4
                    af[i] = *(const bf16x8*)&PS[row * 64 + (c0 ^ ((row & 7) << 2))];
                }
            }
#pragma unroll
            for (int i = 0; i < 2; i++)
                bf[i] = *(const bf16x8*)(Bp + (size_t)i * 16 * 256 + ks * 32);
#pragma unroll
            for (int mi = 0; mi < 2; mi++)
#pragma unroll
                for (int ni = 0; ni < 2; ni++)
                    acc[mi][ni] = __builtin_amdgcn_mfma_f32_16x16x32_bf16(
                        af[mi], bf[ni], acc[mi][ni], 0, 0, 0);
        }

#pragma unroll
        for (int ni = 0; ni < 2; ni++) {
            const int col = w * 32 + ni * 16 + lr;
            const float bv = bn[col];
#pragma unroll
            for (int mi = 0; mi < 2; mi++) {
#pragma unroll
                for (int r = 0; r < 4; r++) {
                    const int row = mi * 16 + quad * 4 + r;   // local
                    float v = acc[mi][ni][r] + bv;
                    v = v > 0.f ? v : 0.01f * v;
                    S[row * 136 + col] = f2b(v);
                }
            }
        }
    }
    __syncthreads();

    // ---- phase B: h2 cols w*64..w*64+63; reads Hs, then rewrites S as H2 ----
    {
        f32x4 acc[2][4];
#pragma unroll
        for (int i = 0; i < 2; i++)
#pragma unroll
            for (int j = 0; j < 4; j++) acc[i][j] = (f32x4){0.f, 0.f, 0.f, 0.f};

        const unsigned short* Bp = W1_b + (size_t)(w * 64 + lr) * 128 + quad * 8;

#pragma unroll
        for (int ks = 0; ks < 4; ks++) {
            bf16x8 af[2], bfr[4];
#pragma unroll
            for (int i = 0; i < 2; i++)
                af[i] = *(const bf16x8*)&S[(i * 16 + lr) * 136 + ks * 32 + quad * 8];
#pragma unroll
            for (int i = 0; i < 4; i++)
                bfr[i] = *(const bf16x8*)(Bp + (size_t)i * 16 * 128 + ks * 32);
#pragma unroll
            for (int mi = 0; mi < 2; mi++)
#pragma unroll
                for (int ni = 0; ni < 4; ni++)
                    acc[mi][ni] = __builtin_amdgcn_mfma_f32_16x16x32_bf16(
                        af[mi], bfr[ni], acc[mi][ni], 0, 0, 0);
        }
        __syncthreads();   // all Hs reads done before S is rewritten as H2

#pragma unroll
        for (int ni = 0; ni < 4; ni++) {
            const int col = w * 64 + ni * 16 + lr;
            const float bv = b1[col];
#pragma unroll
            for (int mi = 0; mi < 2; mi++) {
#pragma unroll
                for (int r = 0; r < 4; r++) {
                    const int row = mi * 16 + quad * 4 + r;   // local
                    float v = acc[mi][ni][r] + bv;
                    v = v > 0.f ? v : 0.01f * v;
                    S[row * 264 + col] = f2b(v);
                }
            }
        }
    }
    __syncthreads();

    // ---- head: waves 0,1 only (16 rows each, full K=256) ----
    if (w < 2) {
        const int m0 = w * 16;
        f32x4 a2 = (f32x4){0.f, 0.f, 0.f, 0.f};
#pragma unroll
        for (int ks = 0; ks < 8; ks++) {
            bf16x8 a = *(const bf16x8*)&S[(m0 + lr) * 264 + ks * 32 + quad * 8];
            bf16x8 bb = *(const bf16x8*)(W2_b + (size_t)lr * 256 + ks * 32 + quad * 8);
            a2 = __builtin_amdgcn_mfma_f32_16x16x32_bf16(a, bb, a2, 0, 0, 0);
        }
        const float bv = b2[lr];
#pragma unroll
        for (int r = 0; r < 4; r++) {
            const int row = row0 + m0 + quad * 4 + r;
            float v = a2[r] + bv;
            out[(size_t)row * 16 + lr] = 1.f / (1.f + __expf(-v));
        }
    }
}

// ---------------------------------------------------------------------------
extern "C" void kernel_launch(void* const* d_in, const int* in_sizes, int n_in,
                              void* d_out, int out_size, void* d_ws, size_t ws_size,
                              hipStream_t stream)
{
    const float* x  = (const float*)d_in[0];
    const float* Wp = (const float*)d_in[1];
    const float* bp = (const float*)d_in[2];
    const float* Ws = (const float*)d_in[3];
    const float* Wn = (const float*)d_in[4];
    const float* bn = (const float*)d_in[5];
    const float* W1 = (const float*)d_in[6];
    const float* b1 = (const float*)d_in[7];
    const float* W2 = (const float*)d_in[8];
    const float* b2 = (const float*)d_in[9];
    const int* src  = (const int*)d_in[10];
    const int* dst  = (const int*)d_in[11];
    float* out = (float*)d_out;

    const int N = in_sizes[0] / 128;   // 65536

    // ws layout:
    //   [ 0,16M)  y  : [N,128] bf16
    //   [16M,32M) xb : [N,128] bf16
    //   [32M,..)  Wcat (128x256 bf16), W1_b (256x128), W2_b (16x256),
    //             bcnt (2048 ints), pairs (2048*BCAP uints ~6.3MB)
    unsigned short* y    = (unsigned short*)d_ws;
    unsigned short* xb   = (unsigned short*)((char*)d_ws + (size_t)16 * 1024 * 1024);
    unsigned short* Wcat = (unsigned short*)((char*)d_ws + (size_t)32 * 1024 * 1024);
    unsigned short* W1_b = Wcat + 32768;
    unsigned short* W2_b = W1_b + 32768;
    int* bcnt = (int*)(W2_b + 4096);
    unsigned int* pairs = (unsigned int*)(bcnt + 2048);

    dim3 blk(256);

    hipMemsetAsync(bcnt, 0, 2048 * sizeof(int), stream);

    // scatter (256) | k1+xb (512) | weight convert (272)
    mega0<<<1040, blk, 0, stream>>>(src, dst, bcnt, pairs,
                                    x, Wp, bp, Ws, Wn, W1, W2,
                                    Wcat, W1_b, W2_b, y, xb);

    // pool + k4 + k5 fused: pooled, h, h2 all live in LDS only
    megaB<<<N / 32, blk, 0, stream>>>((const unsigned int*)y, bcnt, pairs,
                                      xb, Wcat, bn, W1_b, b1, W2_b, b2, out);
}

// Round 6
// 205.353 us; speedup vs baseline: 1.0765x; 1.0043x over previous
//
#include <hip/hip_runtime.h>
#include <cstdint>
#include <cstddef>

typedef __attribute__((ext_vector_type(8))) __bf16 bf16x8;
typedef __attribute__((ext_vector_type(4))) float f32x4;

union bf8pack { unsigned short u[8]; bf16x8 v; uint4 q; };

// Fixed bucket capacity: bucket = 32 dst nodes, mean 512 edges, sigma~22.6.
// 768 = mean + 11 sigma -> overflow probability ~1e-29.
#define BCAP 768

static __device__ __forceinline__ unsigned short f2b(float f) {
    union { float f; unsigned int u; } v; v.f = f;
    unsigned int u = v.u;
    unsigned int r = (u + 0x7fffu + ((u >> 16) & 1u)) >> 16;  // RNE
    return (unsigned short)r;
}

// convert 8 consecutive fp32 -> bf16x8 (RNE)
static __device__ __forceinline__ bf16x8 cvt8(const float* __restrict__ p) {
    float4 f0 = *(const float4*)p;
    float4 f1 = *(const float4*)(p + 4);
    bf8pack pk;
    pk.u[0] = f2b(f0.x); pk.u[1] = f2b(f0.y);
    pk.u[2] = f2b(f0.z); pk.u[3] = f2b(f0.w);
    pk.u[4] = f2b(f1.x); pk.u[5] = f2b(f1.y);
    pk.u[6] = f2b(f1.z); pk.u[7] = f2b(f1.w);
    return pk.v;
}

// packed u16 max: for NON-NEGATIVE bf16 (relu output), integer u16 compare
// == float compare, so one VOP3P op does max of 2 bf16 pairs.
static __device__ __forceinline__ unsigned int pkmax(unsigned int a, unsigned int b) {
    unsigned int d;
    asm("v_pk_max_u16 %0, %1, %2" : "=v"(d) : "v"(a), "v"(b));
    return d;
}

// ---------------------------------------------------------------------------
// mega0 (R5 verbatim): one dispatch, three independent jobs.
//   blocks [0,256)    : edge scatter
//   blocks [256,768)  : k1  y = relu(x @ Wp^T + bp) + xb = bf16(x)
//   blocks [768,1040) : weight convert Wcat/W1_b/W2_b (consumed later)
// ---------------------------------------------------------------------------
__global__ __launch_bounds__(256) void mega0(
    const int* __restrict__ src, const int* __restrict__ dst,
    int* __restrict__ bcnt, unsigned int* __restrict__ pairs,
    const float* __restrict__ x, const float* __restrict__ Wp,
    const float* __restrict__ bp,
    const float* __restrict__ Ws, const float* __restrict__ Wn,
    const float* __restrict__ W1, const float* __restrict__ W2,
    unsigned short* __restrict__ Wcat, unsigned short* __restrict__ W1_b,
    unsigned short* __restrict__ W2_b, unsigned short* __restrict__ y,
    unsigned short* __restrict__ xb)
{
    const int tid = threadIdx.x;
    const int bx = (int)blockIdx.x;

    if (bx >= 768) {            // ---- weight convert (tail blocks) ----
        int i = (bx - 768) * 256 + tid;
        if (i < 32768) {
            int o = i >> 8, k = i & 255;
            Wcat[i] = f2b(k < 128 ? Ws[o * 128 + k] : Wn[o * 128 + (k - 128)]);
        } else if (i < 65536) {
            W1_b[i - 32768] = f2b(W1[i - 32768]);
        } else {                // i < 69632
            W2_b[i - 65536] = f2b(W2[i - 65536]);
        }
        return;
    }

    if (bx >= 256) {            // ---- k1: y = relu(x @ Wp^T + bp) + xb ----
        const int bm = bx - 256;
        const int w  = tid >> 6;
        const int wm = w & 1, wn = w >> 1;
        const int l  = tid & 63;
        const int lr = l & 15, quad = l >> 4;
        const int m0 = bm * 128 + wm * 64;
        const int n0 = wn * 64;

        f32x4 acc[4][4];
#pragma unroll
        for (int i = 0; i < 4; i++)
#pragma unroll
            for (int j = 0; j < 4; j++) acc[i][j] = (f32x4){0.f, 0.f, 0.f, 0.f};

        const float* Apf = x  + (size_t)(m0 + lr) * 128 + quad * 8;
        const float* Bpf = Wp + (size_t)(n0 + lr) * 128 + quad * 8;

#pragma unroll
        for (int ks = 0; ks < 4; ks++) {
            bf16x8 af[4], bf[4];
#pragma unroll
            for (int i = 0; i < 4; i++) {
                const float* p = Apf + (size_t)i * 16 * 128 + ks * 32;
                float4 f0 = *(const float4*)p;
                float4 f1 = *(const float4*)(p + 4);
                bf8pack pk;
                pk.u[0] = f2b(f0.x); pk.u[1] = f2b(f0.y);
                pk.u[2] = f2b(f0.z); pk.u[3] = f2b(f0.w);
                pk.u[4] = f2b(f1.x); pk.u[5] = f2b(f1.y);
                pk.u[6] = f2b(f1.z); pk.u[7] = f2b(f1.w);
                af[i] = pk.v;
                if (wn == 0)   // materialize xb once (waves w=0,1 cover all rows)
                    *(uint4*)(xb + (size_t)(m0 + lr + i * 16) * 128 + ks * 32 + quad * 8) = pk.q;
            }
#pragma unroll
            for (int i = 0; i < 4; i++)
                bf[i] = cvt8(Bpf + (size_t)i * 16 * 128 + ks * 32);
#pragma unroll
            for (int mi = 0; mi < 4; mi++)
#pragma unroll
                for (int ni = 0; ni < 4; ni++)
                    acc[mi][ni] = __builtin_amdgcn_mfma_f32_16x16x32_bf16(
                        af[mi], bf[ni], acc[mi][ni], 0, 0, 0);
        }

#pragma unroll
        for (int ni = 0; ni < 4; ni++) {
            const int col = n0 + ni * 16 + lr;
            const float bv = bp[col];
#pragma unroll
            for (int mi = 0; mi < 4; mi++) {
#pragma unroll
                for (int r = 0; r < 4; r++) {
                    const int row = m0 + mi * 16 + quad * 4 + r;
                    float v = acc[mi][ni][r] + bv;
                    v = v > 0.f ? v : 0.f;
                    y[(size_t)row * 128 + col] = f2b(v);
                }
            }
        }
        return;
    }

    // ---- scatter (blocks 0..255) ----
    __shared__ int h[2048];
    __shared__ int base_l[2048];
    __shared__ int cnt[2048];
    for (int i = tid; i < 2048; i += 256) { h[i] = 0; cnt[i] = 0; }
    __syncthreads();
    const int base = bx * 4096;
    int d_r[16], s_r[16];
    const int4* s4 = (const int4*)(src + base);
    const int4* d4 = (const int4*)(dst + base);
#pragma unroll
    for (int i = 0; i < 4; i++) {
        int4 dv = d4[tid + i * 256];
        int4 sv = s4[tid + i * 256];
        d_r[i * 4 + 0] = dv.x; d_r[i * 4 + 1] = dv.y;
        d_r[i * 4 + 2] = dv.z; d_r[i * 4 + 3] = dv.w;
        s_r[i * 4 + 0] = sv.x; s_r[i * 4 + 1] = sv.y;
        s_r[i * 4 + 2] = sv.z; s_r[i * 4 + 3] = sv.w;
    }
#pragma unroll
    for (int i = 0; i < 16; i++)
        atomicAdd(&h[((unsigned)d_r[i]) >> 5], 1);
    __syncthreads();
    for (int i = tid; i < 2048; i += 256)
        base_l[i] = h[i] ? (i * BCAP + atomicAdd(&bcnt[i], h[i])) : 0;
    __syncthreads();
#pragma unroll
    for (int i = 0; i < 16; i++) {
        int b = ((unsigned)d_r[i]) >> 5;
        int pos = base_l[b] + atomicAdd(&cnt[b], 1);
        if (pos < (b + 1) * BCAP)   // inert guard (overflow impossible at +11 sigma)
            pairs[pos] = ((unsigned)s_r[i] << 5) | ((unsigned)d_r[i] & 31u);
    }
}

// ---------------------------------------------------------------------------
// megaB v2: pool + k45 fused; pool phase rebuilt for latency+VALU
// (R5 diagnosis: VALUBusy 27%, MfmaUtil 4%, no pipe saturated — the 16
// dependent 8-deep gather rounds/wave + shift/mask bf16 fmax were the cost).
//   pool: histogram -> wave-parallel padded scan -> scatter -> pad-fill ->
//         4-node interleaved gather (32 loads in flight/wave, ~5 dependent
//         rounds) with v_pk_max_u16 accumulate (1 op per bf16 pair; valid
//         since y >= 0) -> PS (LDS, XOR-swizzled, R5-proven layout)
//   phase A/B/head: R5 verbatim.
// LDS 19.3K; launch_bounds(256,4): VGPR<=128, no spill (R2 lesson).
// ---------------------------------------------------------------------------
__global__ __launch_bounds__(256, 4) void megaB(
    const unsigned int* __restrict__ yu, const int* __restrict__ bcnt,
    const unsigned int* __restrict__ pairs,
    const unsigned short* __restrict__ xb,
    const unsigned short* __restrict__ Wcat, const float* __restrict__ bn,
    const unsigned short* __restrict__ W1_b, const float* __restrict__ b1,
    const unsigned short* __restrict__ W2_b, const float* __restrict__ b2,
    float* __restrict__ out)
{
    __shared__ unsigned short S[32 * 264];   // Hs[32][136]+PS | then H2[32][264]
    __shared__ unsigned short ldsSrc[1024];
    __shared__ int bin[32], offl[32], cnt2[32];
    unsigned int* PS = (unsigned int*)&S[32 * 136];   // pooled[32][64] u32, swizzled

    const int b = blockIdx.x;
    const int tid = threadIdx.x;
    const int w = tid >> 6, l = tid & 63;
    const int lr = l & 15, quad = l >> 4;
    const int row0 = b * 32;

    // ---- pool: histogram ----
    if (tid < 32) { bin[tid] = 0; cnt2[tid] = 0; }
    __syncthreads();
    const int beg = b * BCAP;
    int nb = bcnt[b]; nb = nb < BCAP ? nb : BCAP;

    for (int i = tid; i < nb; i += 256)
        atomicAdd(&bin[pairs[beg + i] & 31u], 1);
    __syncthreads();

    // ---- wave-parallel exclusive scan of PADDED counts (mult of 8) ----
    // padded total <= 768 + 31*7 = 985 <= 1024 (ldsSrc capacity).
    if (tid < 32) {
        int c = bin[tid];
        int p = (c + 7) & ~7;          // 0 stays 0
        int s = p;
#pragma unroll
        for (int d = 1; d < 32; d <<= 1) {
            int t = __shfl_up(s, d);
            if (tid >= d) s += t;
        }
        offl[tid] = s - p;             // exclusive prefix (multiple of 8)
    }
    __syncthreads();

    // ---- scatter pairs into per-node lists ----
    for (int i = tid; i < nb; i += 256) {
        unsigned int p = pairs[beg + i];
        int d = p & 31u;
        int slot = offl[d] + atomicAdd(&cnt2[d], 1);
        ldsSrc[slot] = (unsigned short)(p >> 5);
    }
    __syncthreads();

    // ---- pad-fill: duplicate last element up to multiple of 8 ----
    if (tid < 32) {
        int c = bin[tid];
        if (c > 0) {
            int o = offl[tid];
            unsigned short last = ldsSrc[o + c - 1];
            int p = (c + 7) & ~7;
            for (int k = c; k < p; k++) ldsSrc[o + k] = last;
        }
    }
    __syncthreads();

    // ---- 4-node interleaved gather: 32 loads in flight per wave ----
    const unsigned int* __restrict__ ylane = yu + l;
#pragma unroll
    for (int g = 0; g < 2; g++) {
        const int n0 = w * 8 + g * 4;
        unsigned int acc[4] = {0u, 0u, 0u, 0u};
        int e0a[4], rka[4];
#pragma unroll
        for (int k = 0; k < 4; k++) {
            e0a[k] = offl[n0 + k];
            rka[k] = (bin[n0 + k] + 7) >> 3;   // padded rounds of 8
        }
        int maxr = rka[0];
#pragma unroll
        for (int k = 1; k < 4; k++) maxr = rka[k] > maxr ? rka[k] : maxr;

        for (int r = 0; r < maxr; r++) {
            unsigned int vv[4][8];
            // issue phase: all loads first (wave-uniform branches)
#pragma unroll
            for (int k = 0; k < 4; k++) {
                if (r < rka[k]) {
                    uint4 sv = *(const uint4*)&ldsSrc[e0a[k] + r * 8];  // 16B-aligned
                    vv[k][0] = ylane[(size_t)(sv.x & 0xffffu) << 6];
                    vv[k][1] = ylane[(size_t)(sv.x >> 16) << 6];
                    vv[k][2] = ylane[(size_t)(sv.y & 0xffffu) << 6];
                    vv[k][3] = ylane[(size_t)(sv.y >> 16) << 6];
                    vv[k][4] = ylane[(size_t)(sv.z & 0xffffu) << 6];
                    vv[k][5] = ylane[(size_t)(sv.z >> 16) << 6];
                    vv[k][6] = ylane[(size_t)(sv.w & 0xffffu) << 6];
                    vv[k][7] = ylane[(size_t)(sv.w >> 16) << 6];
                }
            }
            // consume phase: tree pk_max (depth 3)
#pragma unroll
            for (int k = 0; k < 4; k++) {
                if (r < rka[k]) {
                    unsigned int m01 = pkmax(vv[k][0], vv[k][1]);
                    unsigned int m23 = pkmax(vv[k][2], vv[k][3]);
                    unsigned int m45 = pkmax(vv[k][4], vv[k][5]);
                    unsigned int m67 = pkmax(vv[k][6], vv[k][7]);
                    acc[k] = pkmax(acc[k], pkmax(pkmax(m01, m23), pkmax(m45, m67)));
                }
            }
        }
#pragma unroll
        for (int k = 0; k < 4; k++) {
            const int n = n0 + k;
            // swizzled write (R5-proven): lane l -> u32 col l ^ ((n&7)<<2)
            PS[n * 64 + (l ^ ((n & 7) << 2))] = acc[k];
        }
    }
    __syncthreads();

    // ---- phase A: wave w -> h cols w*32..w*32+31, all 32 rows ----
    {
        f32x4 acc[2][2];
#pragma unroll
        for (int i = 0; i < 2; i++)
#pragma unroll
            for (int j = 0; j < 2; j++) acc[i][j] = (f32x4){0.f, 0.f, 0.f, 0.f};

        const unsigned short* Axp = xb + (size_t)(row0 + lr) * 128 + quad * 8;
        const unsigned short* Bp = Wcat + (size_t)(w * 32 + lr) * 256 + quad * 8;

#pragma unroll
        for (int ks = 0; ks < 8; ks++) {
            bf16x8 af[2], bf[2];
            if (ks < 4) {       // k 0..127: A = xb (bf16, L2/L3-warm, no cvt)
#pragma unroll
                for (int i = 0; i < 2; i++)
                    af[i] = *(const bf16x8*)(Axp + (size_t)i * 16 * 128 + ks * 32);
            } else {            // k 128..255: A = pooled from LDS (swizzled)
#pragma unroll
                for (int i = 0; i < 2; i++) {
                    const int row = i * 16 + lr;
                    const int c0 = (ks - 4) * 16 + quad * 4;   // u32 col, mult of 4
                    af[i] = *(const bf16x8*)&PS[row * 64 + (c0 ^ ((row & 7) << 2))];
                }
            }
#pragma unroll
            for (int i = 0; i < 2; i++)
                bf[i] = *(const bf16x8*)(Bp + (size_t)i * 16 * 256 + ks * 32);
#pragma unroll
            for (int mi = 0; mi < 2; mi++)
#pragma unroll
                for (int ni = 0; ni < 2; ni++)
                    acc[mi][ni] = __builtin_amdgcn_mfma_f32_16x16x32_bf16(
                        af[mi], bf[ni], acc[mi][ni], 0, 0, 0);
        }

#pragma unroll
        for (int ni = 0; ni < 2; ni++) {
            const int col = w * 32 + ni * 16 + lr;
            const float bv = bn[col];
#pragma unroll
            for (int mi = 0; mi < 2; mi++) {
#pragma unroll
                for (int r = 0; r < 4; r++) {
                    const int row = mi * 16 + quad * 4 + r;   // local
                    float v = acc[mi][ni][r] + bv;
                    v = v > 0.f ? v : 0.01f * v;
                    S[row * 136 + col] = f2b(v);
                }
            }
        }
    }
    __syncthreads();

    // ---- phase B: h2 cols w*64..w*64+63; reads Hs, then rewrites S as H2 ----
    {
        f32x4 acc[2][4];
#pragma unroll
        for (int i = 0; i < 2; i++)
#pragma unroll
            for (int j = 0; j < 4; j++) acc[i][j] = (f32x4){0.f, 0.f, 0.f, 0.f};

        const unsigned short* Bp = W1_b + (size_t)(w * 64 + lr) * 128 + quad * 8;

#pragma unroll
        for (int ks = 0; ks < 4; ks++) {
            bf16x8 af[2], bfr[4];
#pragma unroll
            for (int i = 0; i < 2; i++)
                af[i] = *(const bf16x8*)&S[(i * 16 + lr) * 136 + ks * 32 + quad * 8];
#pragma unroll
            for (int i = 0; i < 4; i++)
                bfr[i] = *(const bf16x8*)(Bp + (size_t)i * 16 * 128 + ks * 32);
#pragma unroll
            for (int mi = 0; mi < 2; mi++)
#pragma unroll
                for (int ni = 0; ni < 4; ni++)
                    acc[mi][ni] = __builtin_amdgcn_mfma_f32_16x16x32_bf16(
                        af[mi], bfr[ni], acc[mi][ni], 0, 0, 0);
        }
        __syncthreads();   // all Hs reads done before S is rewritten as H2

#pragma unroll
        for (int ni = 0; ni < 4; ni++) {
            const int col = w * 64 + ni * 16 + lr;
            const float bv = b1[col];
#pragma unroll
            for (int mi = 0; mi < 2; mi++) {
#pragma unroll
                for (int r = 0; r < 4; r++) {
                    const int row = mi * 16 + quad * 4 + r;   // local
                    float v = acc[mi][ni][r] + bv;
                    v = v > 0.f ? v : 0.01f * v;
                    S[row * 264 + col] = f2b(v);
                }
            }
        }
    }
    __syncthreads();

    // ---- head: waves 0,1 only (16 rows each, full K=256) ----
    if (w < 2) {
        const int m0 = w * 16;
        f32x4 a2 = (f32x4){0.f, 0.f, 0.f, 0.f};
#pragma unroll
        for (int ks = 0; ks < 8; ks++) {
            bf16x8 a = *(const bf16x8*)&S[(m0 + lr) * 264 + ks * 32 + quad * 8];
            bf16x8 bb = *(const bf16x8*)(W2_b + (size_t)lr * 256 + ks * 32 + quad * 8);
            a2 = __builtin_amdgcn_mfma_f32_16x16x32_bf16(a, bb, a2, 0, 0, 0);
        }
        const float bv = b2[lr];
#pragma unroll
        for (int r = 0; r < 4; r++) {
            const int row = row0 + m0 + quad * 4 + r;
            float v = a2[r] + bv;
            out[(size_t)row * 16 + lr] = 1.f / (1.f + __expf(-v));
        }
    }
}

// ---------------------------------------------------------------------------
extern "C" void kernel_launch(void* const* d_in, const int* in_sizes, int n_in,
                              void* d_out, int out_size, void* d_ws, size_t ws_size,
                              hipStream_t stream)
{
    const float* x  = (const float*)d_in[0];
    const float* Wp = (const float*)d_in[1];
    const float* bp = (const float*)d_in[2];
    const float* Ws = (const float*)d_in[3];
    const float* Wn = (const float*)d_in[4];
    const float* bn = (const float*)d_in[5];
    const float* W1 = (const float*)d_in[6];
    const float* b1 = (const float*)d_in[7];
    const float* W2 = (const float*)d_in[8];
    const float* b2 = (const float*)d_in[9];
    const int* src  = (const int*)d_in[10];
    const int* dst  = (const int*)d_in[11];
    float* out = (float*)d_out;

    const int N = in_sizes[0] / 128;   // 65536

    // ws layout:
    //   [ 0,16M)  y  : [N,128] bf16
    //   [16M,32M) xb : [N,128] bf16
    //   [32M,..)  Wcat (128x256 bf16), W1_b (256x128), W2_b (16x256),
    //             bcnt (2048 ints), pairs (2048*BCAP uints ~6.3MB)
    unsigned short* y    = (unsigned short*)d_ws;
    unsigned short* xb   = (unsigned short*)((char*)d_ws + (size_t)16 * 1024 * 1024);
    unsigned short* Wcat = (unsigned short*)((char*)d_ws + (size_t)32 * 1024 * 1024);
    unsigned short* W1_b = Wcat + 32768;
    unsigned short* W2_b = W1_b + 32768;
    int* bcnt = (int*)(W2_b + 4096);
    unsigned int* pairs = (unsigned int*)(bcnt + 2048);

    dim3 blk(256);

    hipMemsetAsync(bcnt, 0, 2048 * sizeof(int), stream);

    // scatter (256) | k1+xb (512) | weight convert (272)
    mega0<<<1040, blk, 0, stream>>>(src, dst, bcnt, pairs,
                                    x, Wp, bp, Ws, Wn, W1, W2,
                                    Wcat, W1_b, W2_b, y, xb);

    // pool + k4 + k5 fused: pooled, h, h2 all live in LDS only
    megaB<<<N / 32, blk, 0, stream>>>((const unsigned int*)y, bcnt, pairs,
                                      xb, Wcat, bn, W1_b, b1, W2_b, b2, out);
}